// Round 1
// baseline (16739.651 us; speedup 1.0000x reference)
//
#include <hip/hip_runtime.h>
#include <hip/hip_bf16.h>
#include <stdint.h>

#define NN 100000
#define DD 256
#define EE 1600000

typedef short s16x8 __attribute__((ext_vector_type(8)));
typedef float f32x4 __attribute__((ext_vector_type(4)));

__device__ __forceinline__ unsigned short f2bf(float f) {
    union { float f; unsigned int u; } un; un.f = f;
    unsigned int u = un.u;
    unsigned int r = u + 0x7fffu + ((u >> 16) & 1u);  // RNE
    return (unsigned short)(r >> 16);
}

// ---- Convert a 256x256 f32 weight (row-major, W[k][n]) into MFMA B-fragment order:
// Wf[((s*16 + c)*64 + lane)*8 + j] = bf16( W[(s*32 + (lane>>4)*8 + j)*256 + (c*16 + (lane&15))] )
__global__ void k_wconv(const float* __restrict__ W, unsigned short* __restrict__ Wf) {
    int t = blockIdx.x * 256 + threadIdx.x;   // 65536 total
    int j = t & 7;
    int l = (t >> 3) & 63;
    int c = (t >> 9) & 15;
    int s = t >> 13;
    int k   = s * 32 + (l >> 4) * 8 + j;
    int col = c * 16 + (l & 15);
    Wf[t] = f2bf(W[k * 256 + col]);
}

__global__ void k_copy(const float4* __restrict__ in, float4* __restrict__ out, int n) {
    for (int i = blockIdx.x * blockDim.x + threadIdx.x; i < n; i += gridDim.x * blockDim.x)
        out[i] = in[i];
}

// one wave per edge: lane reads float4 of h[src], atomic-adds into agg[dst]
__global__ void k_scatter(const float* __restrict__ h, const int* __restrict__ src,
                          const int* __restrict__ dst, float* __restrict__ agg) {
    long long gid = (long long)blockIdx.x * blockDim.x + threadIdx.x;
    int e = (int)(gid >> 6);
    int lane = (int)(gid & 63);
    if (e < EE) {
        int s = src[e];
        int d = dst[e];
        float4 v = *(const float4*)(h + (size_t)s * DD + lane * 4);
        float* p = agg + (size_t)d * DD + lane * 4;
        atomicAdd(p + 0, v.x);
        atomicAdd(p + 1, v.y);
        atomicAdd(p + 2, v.z);
        atomicAdd(p + 3, v.w);
    }
}

// C[M x 256] = A[M x 256] @ W[256 x 256] + bias.  A f32 (converted inline to bf16),
// Wf in fragment order (see k_wconv). Block: 64 rows x 256 cols, 4 waves (2x2).
// In-place safe (C==A): each block stages its own 64 A-rows into LDS before writing.
__launch_bounds__(256)
__global__ void k_gemm(const float* __restrict__ A, const unsigned short* __restrict__ Wf,
                       const float* __restrict__ bias, float* __restrict__ C, int M) {
    __shared__ s16x8 Al[2048];   // 64 rows x 256 cols bf16 = 32 KB, XOR-swizzled
    const int bm = blockIdx.x;
    const int tid = threadIdx.x;
    const int base_row = bm * 64;

    // ---- stage A (f32 -> bf16) into LDS
    #pragma unroll
    for (int i = 0; i < 8; i++) {
        int chunk = tid + i * 256;        // 0..2047 ; 8 bf16 per chunk
        int row = chunk >> 5;             // 0..63
        int k0  = (chunk & 31) * 8;       // 0..248
        int gr = base_row + row;
        float4 v0, v1;
        if (gr < M) {
            const float4* gp = (const float4*)(A + (size_t)gr * 256 + k0);
            v0 = gp[0]; v1 = gp[1];
        } else {
            v0 = make_float4(0.f, 0.f, 0.f, 0.f);
            v1 = make_float4(0.f, 0.f, 0.f, 0.f);
        }
        s16x8 sv;
        sv[0] = (short)f2bf(v0.x); sv[1] = (short)f2bf(v0.y);
        sv[2] = (short)f2bf(v0.z); sv[3] = (short)f2bf(v0.w);
        sv[4] = (short)f2bf(v1.x); sv[5] = (short)f2bf(v1.y);
        sv[6] = (short)f2bf(v1.z); sv[7] = (short)f2bf(v1.w);
        int byte = (row * 512 + k0 * 2) ^ ((row & 7) << 4);
        Al[byte >> 4] = sv;
    }
    __syncthreads();

    const int lane = tid & 63;
    const int w = tid >> 6;
    const int wr = w >> 1;     // 0..1 : 32-row half
    const int wc = w & 1;      // 0..1 : 128-col half

    f32x4 acc[2][8];
    #pragma unroll
    for (int m = 0; m < 2; m++)
        #pragma unroll
        for (int c = 0; c < 8; c++)
            acc[m][c] = (f32x4){0.f, 0.f, 0.f, 0.f};

    #pragma unroll
    for (int s = 0; s < 8; s++) {        // K steps of 32
        s16x8 a[2], b[8];
        #pragma unroll
        for (int m = 0; m < 2; m++) {
            int row = wr * 32 + m * 16 + (lane & 15);
            int koff = s * 32 + (lane >> 4) * 8;
            int byte = (row * 512 + koff * 2) ^ ((row & 7) << 4);
            a[m] = Al[byte >> 4];
        }
        const unsigned short* wp = Wf + (size_t)((s * 16 + wc * 8) * 64 + lane) * 8;
        #pragma unroll
        for (int c = 0; c < 8; c++)
            b[c] = *(const s16x8*)(wp + (size_t)c * 512);
        #pragma unroll
        for (int m = 0; m < 2; m++)
            #pragma unroll
            for (int c = 0; c < 8; c++)
                acc[m][c] = __builtin_amdgcn_mfma_f32_16x16x32_bf16(a[m], b[c], acc[m][c], 0, 0, 0);
    }

    // ---- epilogue: D row = (lane>>4)*4 + r, col = lane&15  (m89-verified layout)
    #pragma unroll
    for (int m = 0; m < 2; m++) {
        int row0 = base_row + wr * 32 + m * 16 + (lane >> 4) * 4;
        #pragma unroll
        for (int c = 0; c < 8; c++) {
            int col = wc * 128 + c * 16 + (lane & 15);
            float bv = bias[col];
            #pragma unroll
            for (int r = 0; r < 4; r++) {
                int row = row0 + r;
                if (row < M) C[(size_t)row * 256 + col] = acc[m][c][r] + bv;
            }
        }
    }
}

// per-column sum and sum-of-squares over M rows (two-level: serial + atomics)
__global__ void k_stats(const float* __restrict__ z, float* __restrict__ s1,
                        float* __restrict__ s2, int M) {
    int col = threadIdx.x;
    float a = 0.f, b = 0.f;
    for (int r = blockIdx.x; r < M; r += gridDim.x) {
        float v = z[(size_t)r * DD + col];
        a += v;
        b += v * v;
    }
    atomicAdd(&s1[col], a);
    atomicAdd(&s2[col], b);
}

// in-place z = relu( (z - mean) * rsqrt(var+eps) * g + be )
__global__ void k_bnrelu(float* __restrict__ z, const float* __restrict__ s1,
                         const float* __restrict__ s2, const float* __restrict__ g,
                         const float* __restrict__ be, int M) {
    int t = threadIdx.x;
    float mean = s1[t] * (1.0f / NN);
    float var  = s2[t] * (1.0f / NN) - mean * mean;
    float k = rsqrtf(var + 1e-5f) * g[t];
    float sh = be[t] - mean * k;
    for (int r = blockIdx.x; r < M; r += gridDim.x) {
        float v = z[(size_t)r * DD + t];
        v = v * k + sh;
        z[(size_t)r * DD + t] = v > 0.f ? v : 0.f;
    }
}

extern "C" void kernel_launch(void* const* d_in, const int* in_sizes, int n_in,
                              void* d_out, int out_size, void* d_ws, size_t ws_size,
                              hipStream_t stream) {
    const float* x   = (const float*)d_in[0];
    const int*   src = (const int*)d_in[1];
    const int*   dst = (const int*)d_in[2];
    // dict order: x,src,dst, l0:{w1,b1,g1,be1,w2,b2,g2,be2}, l1:{...}, l2:{w1,b1,g1,be1,w2,b2}
    const float* W[6]    = { (const float*)d_in[3],  (const float*)d_in[7],
                             (const float*)d_in[11], (const float*)d_in[15],
                             (const float*)d_in[19], (const float*)d_in[23] };
    const float* Bias[6] = { (const float*)d_in[4],  (const float*)d_in[8],
                             (const float*)d_in[12], (const float*)d_in[16],
                             (const float*)d_in[20], (const float*)d_in[24] };
    const float* Gam[5]  = { (const float*)d_in[5],  (const float*)d_in[9],
                             (const float*)d_in[13], (const float*)d_in[17],
                             (const float*)d_in[21] };
    const float* Bet[5]  = { (const float*)d_in[6],  (const float*)d_in[10],
                             (const float*)d_in[14], (const float*)d_in[18],
                             (const float*)d_in[22] };

    char* ws = (char*)d_ws;
    unsigned short* Wf = (unsigned short*)ws;          // 6 * 65536 ushort = 786432 B
    float* stats = (float*)(ws + 786432);              // 5 * 512 f32 = 10240 B
    float* WS0 = (float*)(ws + (1 << 20));             // N*D f32 = 102.4 MB
    float* OUT = (float*)d_out;

    for (int i = 0; i < 6; i++)
        k_wconv<<<256, 256, 0, stream>>>(W[i], Wf + (size_t)i * 65536);
    hipMemsetAsync(stats, 0, 5 * 512 * sizeof(float), stream);

    auto copy = [&](const float* in, float* out) {
        k_copy<<<4096, 256, 0, stream>>>((const float4*)in, (float4*)out, NN * DD / 4);
    };
    auto scatter = [&](const float* h, float* agg) {
        k_scatter<<<EE / 4, 256, 0, stream>>>(h, src, dst, agg);
    };
    auto gemm = [&](const float* A, int wi, float* C) {
        k_gemm<<<1563, 256, 0, stream>>>(A, Wf + (size_t)wi * 65536, Bias[wi], C, NN);
    };
    auto stats_bn = [&](float* z, int si) {
        k_stats<<<1024, 256, 0, stream>>>(z, stats + si * 512, stats + si * 512 + 256, NN);
        k_bnrelu<<<2048, 256, 0, stream>>>(z, stats + si * 512, stats + si * 512 + 256,
                                           Gam[si], Bet[si], NN);
    };

    // ---- Layer 0 (h = x)
    copy(x, WS0); scatter(x, WS0);          // agg in WS0
    gemm(WS0, 0, OUT); stats_bn(OUT, 0);    // z1 in OUT
    gemm(OUT, 1, WS0); stats_bn(WS0, 1);    // h1 in WS0

    // ---- Layer 1
    copy(WS0, OUT); scatter(WS0, OUT);      // agg in OUT
    gemm(OUT, 2, WS0); stats_bn(WS0, 2);    // z1 in WS0 (h1 dead)
    gemm(WS0, 3, OUT); stats_bn(OUT, 3);    // h2 in OUT

    // ---- Layer 2
    copy(OUT, WS0); scatter(OUT, WS0);      // agg in WS0
    gemm(WS0, 4, OUT); stats_bn(OUT, 4);    // z1 in OUT (h2 dead)
    gemm(OUT, 5, OUT);                      // final, in-place (block-local rows)
}

// Round 2
// 1642.653 us; speedup vs baseline: 10.1906x; 10.1906x over previous
//
#include <hip/hip_runtime.h>
#include <hip/hip_bf16.h>
#include <stdint.h>

#define NN 100000
#define DD 256
#define EE 1600000
#define NB 391   // ceil(NN/256)

typedef short s16x8 __attribute__((ext_vector_type(8)));
typedef float f32x4 __attribute__((ext_vector_type(4)));

__device__ __forceinline__ unsigned short f2bf(float f) {
    union { float f; unsigned int u; } un; un.f = f;
    unsigned int u = un.u;
    unsigned int r = u + 0x7fffu + ((u >> 16) & 1u);  // RNE
    return (unsigned short)(r >> 16);
}

// ---- weight -> MFMA B-fragment order (see round 1)
__global__ void k_wconv(const float* __restrict__ W, unsigned short* __restrict__ Wf) {
    int t = blockIdx.x * 256 + threadIdx.x;   // 65536 total
    int j = t & 7;
    int l = (t >> 3) & 63;
    int c = (t >> 9) & 15;
    int s = t >> 13;
    int k   = s * 32 + (l >> 4) * 8 + j;
    int col = c * 16 + (l & 15);
    Wf[t] = f2bf(W[k * 256 + col]);
}

// ================= CSR build =================
__global__ void k_deghist(const int* __restrict__ dst, int* __restrict__ deg) {
    int e = blockIdx.x * 256 + threadIdx.x;
    atomicAdd(&deg[dst[e]], 1);
}

__global__ void k_blocksum(const int* __restrict__ deg, int* __restrict__ bsum) {
    __shared__ int s[256];
    int t = blockIdx.x * 256 + threadIdx.x;
    s[threadIdx.x] = (t < NN) ? deg[t] : 0;
    __syncthreads();
    for (int off = 128; off > 0; off >>= 1) {
        if (threadIdx.x < off) s[threadIdx.x] += s[threadIdx.x + off];
        __syncthreads();
    }
    if (threadIdx.x == 0) bsum[blockIdx.x] = s[0];
}

// single block: exclusive scan of NB block sums -> boff; rowptr[NN] = EE
__global__ void k_scanb(const int* __restrict__ bsum, int* __restrict__ boff,
                        int* __restrict__ rowptr) {
    __shared__ int s[512];
    int tid = threadIdx.x;
    s[tid] = (tid < NB) ? bsum[tid] : 0;
    __syncthreads();
    for (int off = 1; off < 512; off <<= 1) {
        int x = 0;
        if (tid >= off) x = s[tid - off];
        __syncthreads();
        if (tid >= off) s[tid] += x;
        __syncthreads();
    }
    if (tid < NB) boff[tid] = (tid > 0) ? s[tid - 1] : 0;
    if (tid == 0) rowptr[NN] = EE;
}

__global__ void k_finalscan(const int* __restrict__ deg, const int* __restrict__ boff,
                            int* __restrict__ rowptr) {
    __shared__ int s[256];
    int tid = threadIdx.x;
    int t = blockIdx.x * 256 + tid;
    int v = (t < NN) ? deg[t] : 0;
    s[tid] = v;
    __syncthreads();
    for (int off = 1; off < 256; off <<= 1) {
        int x = 0;
        if (tid >= off) x = s[tid - off];
        __syncthreads();
        if (tid >= off) s[tid] += x;
        __syncthreads();
    }
    if (t < NN) rowptr[t] = boff[blockIdx.x] + s[tid] - v;  // exclusive
}

__global__ void k_fill(const int* __restrict__ src, const int* __restrict__ dst,
                       const int* __restrict__ rowptr, int* __restrict__ cur,
                       int* __restrict__ eidx) {
    int e = blockIdx.x * 256 + threadIdx.x;
    int d = dst[e];
    int pos = atomicAdd(&cur[d], 1);
    eidx[rowptr[d] + pos] = src[e];
}

// ================= gather: agg[v] = h[v] + sum_{u in N(v)} h[u] =================
// one wave per node; lane covers float4 (16B) of the 1KB row
__launch_bounds__(256)
__global__ void k_gather(const float4* __restrict__ h, const int* __restrict__ rowptr,
                         const int* __restrict__ eidx, float4* __restrict__ agg) {
    int gid = blockIdx.x * 256 + threadIdx.x;
    int node = gid >> 6;
    int lane = gid & 63;
    if (node >= NN) return;
    int beg = rowptr[node];
    int end = rowptr[node + 1];
    float4 acc = h[(size_t)node * 64 + lane];
    for (int i = beg; i < end; i++) {
        int s = eidx[i];
        float4 v = h[(size_t)s * 64 + lane];
        acc.x += v.x; acc.y += v.y; acc.z += v.z; acc.w += v.w;
    }
    agg[(size_t)node * 64 + lane] = acc;
}

// ================= GEMM (64x256 block, 4 waves, bf16 MFMA) =================
__launch_bounds__(256)
__global__ void k_gemm(const float* __restrict__ A, const unsigned short* __restrict__ Wf,
                       const float* __restrict__ bias, float* __restrict__ C, int M) {
    __shared__ s16x8 Al[2048];   // 64 rows x 256 cols bf16 = 32 KB, XOR-swizzled
    const int bm = blockIdx.x;
    const int tid = threadIdx.x;
    const int base_row = bm * 64;

    #pragma unroll
    for (int i = 0; i < 8; i++) {
        int chunk = tid + i * 256;
        int row = chunk >> 5;
        int k0  = (chunk & 31) * 8;
        int gr = base_row + row;
        float4 v0, v1;
        if (gr < M) {
            const float4* gp = (const float4*)(A + (size_t)gr * 256 + k0);
            v0 = gp[0]; v1 = gp[1];
        } else {
            v0 = make_float4(0.f, 0.f, 0.f, 0.f);
            v1 = make_float4(0.f, 0.f, 0.f, 0.f);
        }
        s16x8 sv;
        sv[0] = (short)f2bf(v0.x); sv[1] = (short)f2bf(v0.y);
        sv[2] = (short)f2bf(v0.z); sv[3] = (short)f2bf(v0.w);
        sv[4] = (short)f2bf(v1.x); sv[5] = (short)f2bf(v1.y);
        sv[6] = (short)f2bf(v1.z); sv[7] = (short)f2bf(v1.w);
        int byte = (row * 512 + k0 * 2) ^ ((row & 7) << 4);
        Al[byte >> 4] = sv;
    }
    __syncthreads();

    const int lane = tid & 63;
    const int w = tid >> 6;
    const int wr = w >> 1;
    const int wc = w & 1;

    f32x4 acc[2][8];
    #pragma unroll
    for (int m = 0; m < 2; m++)
        #pragma unroll
        for (int c = 0; c < 8; c++)
            acc[m][c] = (f32x4){0.f, 0.f, 0.f, 0.f};

    #pragma unroll
    for (int s = 0; s < 8; s++) {
        s16x8 a[2], b[8];
        #pragma unroll
        for (int m = 0; m < 2; m++) {
            int row = wr * 32 + m * 16 + (lane & 15);
            int koff = s * 32 + (lane >> 4) * 8;
            int byte = (row * 512 + koff * 2) ^ ((row & 7) << 4);
            a[m] = Al[byte >> 4];
        }
        const unsigned short* wp = Wf + (size_t)((s * 16 + wc * 8) * 64 + lane) * 8;
        #pragma unroll
        for (int c = 0; c < 8; c++)
            b[c] = *(const s16x8*)(wp + (size_t)c * 512);
        #pragma unroll
        for (int m = 0; m < 2; m++)
            #pragma unroll
            for (int c = 0; c < 8; c++)
                acc[m][c] = __builtin_amdgcn_mfma_f32_16x16x32_bf16(a[m], b[c], acc[m][c], 0, 0, 0);
    }

    #pragma unroll
    for (int m = 0; m < 2; m++) {
        int row0 = base_row + wr * 32 + m * 16 + (lane >> 4) * 4;
        #pragma unroll
        for (int c = 0; c < 8; c++) {
            int col = wc * 128 + c * 16 + (lane & 15);
            float bv = bias[col];
            #pragma unroll
            for (int r = 0; r < 4; r++) {
                int row = row0 + r;
                if (row < M) C[(size_t)row * 256 + col] = acc[m][c][r] + bv;
            }
        }
    }
}

// ================= BN =================
__global__ void k_stats(const float* __restrict__ z, float* __restrict__ s1,
                        float* __restrict__ s2, int M) {
    int col = threadIdx.x;
    float a = 0.f, b = 0.f;
    for (int r = blockIdx.x; r < M; r += gridDim.x) {
        float v = z[(size_t)r * DD + col];
        a += v;
        b += v * v;
    }
    atomicAdd(&s1[col], a);
    atomicAdd(&s2[col], b);
}

__global__ void k_bnrelu(float* __restrict__ z, const float* __restrict__ s1,
                         const float* __restrict__ s2, const float* __restrict__ g,
                         const float* __restrict__ be, int M) {
    int t = threadIdx.x;
    float mean = s1[t] * (1.0f / NN);
    float var  = s2[t] * (1.0f / NN) - mean * mean;
    float k = rsqrtf(var + 1e-5f) * g[t];
    float sh = be[t] - mean * k;
    for (int r = blockIdx.x; r < M; r += gridDim.x) {
        float v = z[(size_t)r * DD + t];
        v = v * k + sh;
        z[(size_t)r * DD + t] = v > 0.f ? v : 0.f;
    }
}

extern "C" void kernel_launch(void* const* d_in, const int* in_sizes, int n_in,
                              void* d_out, int out_size, void* d_ws, size_t ws_size,
                              hipStream_t stream) {
    const float* x   = (const float*)d_in[0];
    const int*   src = (const int*)d_in[1];
    const int*   dst = (const int*)d_in[2];
    const float* W[6]    = { (const float*)d_in[3],  (const float*)d_in[7],
                             (const float*)d_in[11], (const float*)d_in[15],
                             (const float*)d_in[19], (const float*)d_in[23] };
    const float* Bias[6] = { (const float*)d_in[4],  (const float*)d_in[8],
                             (const float*)d_in[12], (const float*)d_in[16],
                             (const float*)d_in[20], (const float*)d_in[24] };
    const float* Gam[5]  = { (const float*)d_in[5],  (const float*)d_in[9],
                             (const float*)d_in[13], (const float*)d_in[17],
                             (const float*)d_in[21] };
    const float* Bet[5]  = { (const float*)d_in[6],  (const float*)d_in[10],
                             (const float*)d_in[14], (const float*)d_in[18],
                             (const float*)d_in[22] };

    char* ws = (char*)d_ws;
    unsigned short* Wf = (unsigned short*)ws;              // 786,432 B
    float* stats = (float*)(ws + 786432);                  // 10,240 B
    float* WS0 = (float*)(ws + (1 << 20));                 // 102,400,000 B
    char* csr = ws + (1 << 20) + 102400000;
    int* rowptr = (int*)csr;                               // (NN+1) ints
    int* deg    = (int*)(csr + 400128);                    // NN ints
    int* cur    = (int*)(csr + 800128);                    // NN ints
    int* bsum   = (int*)(csr + 1200128);                   // 512 ints
    int* boff   = (int*)(csr + 1202176);                   // 512 ints
    int* eidx   = (int*)(csr + 1204224);                   // EE ints = 6.4 MB
    float* OUT = (float*)d_out;

    // ---- prep: weights + CSR
    for (int i = 0; i < 6; i++)
        k_wconv<<<256, 256, 0, stream>>>(W[i], Wf + (size_t)i * 65536);
    hipMemsetAsync(stats, 0, 5 * 512 * sizeof(float), stream);
    hipMemsetAsync(deg, 0, NN * sizeof(int), stream);
    hipMemsetAsync(cur, 0, NN * sizeof(int), stream);

    k_deghist<<<EE / 256, 256, 0, stream>>>(dst, deg);
    k_blocksum<<<NB, 256, 0, stream>>>(deg, bsum);
    k_scanb<<<1, 512, 0, stream>>>(bsum, boff, rowptr);
    k_finalscan<<<NB, 256, 0, stream>>>(deg, boff, rowptr);
    k_fill<<<EE / 256, 256, 0, stream>>>(src, dst, rowptr, cur, eidx);

    auto gather = [&](const float* h, float* agg) {
        k_gather<<<(NN * 64 + 255) / 256, 256, 0, stream>>>(
            (const float4*)h, rowptr, eidx, (float4*)agg);
    };
    auto gemm = [&](const float* A, int wi, float* C) {
        k_gemm<<<1563, 256, 0, stream>>>(A, Wf + (size_t)wi * 65536, Bias[wi], C, NN);
    };
    auto stats_bn = [&](float* z, int si) {
        k_stats<<<1024, 256, 0, stream>>>(z, stats + si * 512, stats + si * 512 + 256, NN);
        k_bnrelu<<<2048, 256, 0, stream>>>(z, stats + si * 512, stats + si * 512 + 256,
                                           Gam[si], Bet[si], NN);
    };

    // ---- Layer 0 (h = x)
    gather(x, WS0);
    gemm(WS0, 0, OUT); stats_bn(OUT, 0);
    gemm(OUT, 1, WS0); stats_bn(WS0, 1);    // h1 in WS0

    // ---- Layer 1
    gather(WS0, OUT);
    gemm(OUT, 2, WS0); stats_bn(WS0, 2);
    gemm(WS0, 3, OUT); stats_bn(OUT, 3);    // h2 in OUT

    // ---- Layer 2
    gather(OUT, WS0);
    gemm(WS0, 4, OUT); stats_bn(OUT, 4);
    gemm(OUT, 5, OUT);                       // final, in-place
}

// Round 3
// 1244.318 us; speedup vs baseline: 13.4529x; 1.3201x over previous
//
#include <hip/hip_runtime.h>
#include <hip/hip_bf16.h>
#include <stdint.h>

#define NN 100000
#define DD 256
#define EE 1600000
#define NB 391   // ceil(NN/256)

typedef short s16x8 __attribute__((ext_vector_type(8)));
typedef float f32x4 __attribute__((ext_vector_type(4)));

__device__ __forceinline__ unsigned short f2bf(float f) {
    union { float f; unsigned int u; } un; un.f = f;
    unsigned int u = un.u;
    unsigned int r = u + 0x7fffu + ((u >> 16) & 1u);  // RNE
    return (unsigned short)(r >> 16);
}
__device__ __forceinline__ float bf2f(unsigned short s) {
    union { unsigned int u; float f; } c; c.u = (unsigned int)s << 16; return c.f;
}

// ---- weight -> MFMA B-fragment order
__global__ void k_wconv(const float* __restrict__ W, unsigned short* __restrict__ Wf) {
    int t = blockIdx.x * 256 + threadIdx.x;   // 65536 total
    int j = t & 7;
    int l = (t >> 3) & 63;
    int c = (t >> 9) & 15;
    int s = t >> 13;
    int k   = s * 32 + (l >> 4) * 8 + j;
    int col = c * 16 + (l & 15);
    Wf[t] = f2bf(W[k * 256 + col]);
}

// ================= CSR build =================
__global__ void k_deghist(const int* __restrict__ dst, int* __restrict__ deg) {
    int e = blockIdx.x * 256 + threadIdx.x;
    atomicAdd(&deg[dst[e]], 1);
}

__global__ void k_blocksum(const int* __restrict__ deg, int* __restrict__ bsum) {
    __shared__ int s[256];
    int t = blockIdx.x * 256 + threadIdx.x;
    s[threadIdx.x] = (t < NN) ? deg[t] : 0;
    __syncthreads();
    for (int off = 128; off > 0; off >>= 1) {
        if (threadIdx.x < off) s[threadIdx.x] += s[threadIdx.x + off];
        __syncthreads();
    }
    if (threadIdx.x == 0) bsum[blockIdx.x] = s[0];
}

__global__ void k_scanb(const int* __restrict__ bsum, int* __restrict__ boff,
                        int* __restrict__ rowptr) {
    __shared__ int s[512];
    int tid = threadIdx.x;
    s[tid] = (tid < NB) ? bsum[tid] : 0;
    __syncthreads();
    for (int off = 1; off < 512; off <<= 1) {
        int x = 0;
        if (tid >= off) x = s[tid - off];
        __syncthreads();
        if (tid >= off) s[tid] += x;
        __syncthreads();
    }
    if (tid < NB) boff[tid] = (tid > 0) ? s[tid - 1] : 0;
    if (tid == 0) rowptr[NN] = EE;
}

__global__ void k_finalscan(const int* __restrict__ deg, const int* __restrict__ boff,
                            int* __restrict__ rowptr) {
    __shared__ int s[256];
    int tid = threadIdx.x;
    int t = blockIdx.x * 256 + tid;
    int v = (t < NN) ? deg[t] : 0;
    s[tid] = v;
    __syncthreads();
    for (int off = 1; off < 256; off <<= 1) {
        int x = 0;
        if (tid >= off) x = s[tid - off];
        __syncthreads();
        if (tid >= off) s[tid] += x;
        __syncthreads();
    }
    if (t < NN) rowptr[t] = boff[blockIdx.x] + s[tid] - v;  // exclusive
}

__global__ void k_fill(const int* __restrict__ src, const int* __restrict__ dst,
                       const int* __restrict__ rowptr, int* __restrict__ cur,
                       int* __restrict__ eidx) {
    int e = blockIdx.x * 256 + threadIdx.x;
    int d = dst[e];
    int pos = atomicAdd(&cur[d], 1);
    eidx[rowptr[d] + pos] = src[e];
}

// ================= gather =================
// MODE 0: f32 input, no BN (layer 0).  MODE 1: bf16 raw-z input, fused BN+ReLU.
// agg output is bf16. One wave per node.
template<int MODE>
__launch_bounds__(256)
__global__ void k_gather(const void* __restrict__ hv, const int* __restrict__ rowptr,
                         const int* __restrict__ eidx,
                         const float* __restrict__ s1, const float* __restrict__ s2,
                         const float* __restrict__ g, const float* __restrict__ be,
                         ushort4* __restrict__ agg) {
    int gid = blockIdx.x * 256 + threadIdx.x;
    int node = gid >> 6;
    int lane = gid & 63;
    if (node >= NN) return;
    int beg = rowptr[node];
    int end = rowptr[node + 1];
    float4 acc;

    if constexpr (MODE == 0) {
        const float4* h = (const float4*)hv;
        acc = h[(size_t)node * 64 + lane];
        int i = beg;
        for (; i + 1 < end; i += 2) {
            float4 v0 = h[(size_t)eidx[i] * 64 + lane];
            float4 v1 = h[(size_t)eidx[i + 1] * 64 + lane];
            acc.x += v0.x + v1.x; acc.y += v0.y + v1.y;
            acc.z += v0.z + v1.z; acc.w += v0.w + v1.w;
        }
        if (i < end) {
            float4 v = h[(size_t)eidx[i] * 64 + lane];
            acc.x += v.x; acc.y += v.y; acc.z += v.z; acc.w += v.w;
        }
    } else {
        const ushort4* h = (const ushort4*)hv;
        int c0 = lane * 4;
        float4 s1v = *(const float4*)(s1 + c0);
        float4 s2v = *(const float4*)(s2 + c0);
        float4 gv  = *(const float4*)(g + c0);
        float4 bev = *(const float4*)(be + c0);
        float kk[4], sh[4];
        {
            float m, var;
            m = s1v.x * (1.f/NN); var = s2v.x * (1.f/NN) - m*m; kk[0] = rsqrtf(var+1e-5f)*gv.x; sh[0] = bev.x - m*kk[0];
            m = s1v.y * (1.f/NN); var = s2v.y * (1.f/NN) - m*m; kk[1] = rsqrtf(var+1e-5f)*gv.y; sh[1] = bev.y - m*kk[1];
            m = s1v.z * (1.f/NN); var = s2v.z * (1.f/NN) - m*m; kk[2] = rsqrtf(var+1e-5f)*gv.z; sh[2] = bev.z - m*kk[2];
            m = s1v.w * (1.f/NN); var = s2v.w * (1.f/NN) - m*m; kk[3] = rsqrtf(var+1e-5f)*gv.w; sh[3] = bev.w - m*kk[3];
        }
        ushort4 u = h[(size_t)node * 64 + lane];
        acc.x = fmaxf(bf2f(u.x) * kk[0] + sh[0], 0.f);
        acc.y = fmaxf(bf2f(u.y) * kk[1] + sh[1], 0.f);
        acc.z = fmaxf(bf2f(u.z) * kk[2] + sh[2], 0.f);
        acc.w = fmaxf(bf2f(u.w) * kk[3] + sh[3], 0.f);
        int i = beg;
        for (; i + 1 < end; i += 2) {
            ushort4 a = h[(size_t)eidx[i] * 64 + lane];
            ushort4 b = h[(size_t)eidx[i + 1] * 64 + lane];
            acc.x += fmaxf(bf2f(a.x) * kk[0] + sh[0], 0.f) + fmaxf(bf2f(b.x) * kk[0] + sh[0], 0.f);
            acc.y += fmaxf(bf2f(a.y) * kk[1] + sh[1], 0.f) + fmaxf(bf2f(b.y) * kk[1] + sh[1], 0.f);
            acc.z += fmaxf(bf2f(a.z) * kk[2] + sh[2], 0.f) + fmaxf(bf2f(b.z) * kk[2] + sh[2], 0.f);
            acc.w += fmaxf(bf2f(a.w) * kk[3] + sh[3], 0.f) + fmaxf(bf2f(b.w) * kk[3] + sh[3], 0.f);
        }
        if (i < end) {
            ushort4 a = h[(size_t)eidx[i] * 64 + lane];
            acc.x += fmaxf(bf2f(a.x) * kk[0] + sh[0], 0.f);
            acc.y += fmaxf(bf2f(a.y) * kk[1] + sh[1], 0.f);
            acc.z += fmaxf(bf2f(a.z) * kk[2] + sh[2], 0.f);
            acc.w += fmaxf(bf2f(a.w) * kk[3] + sh[3], 0.f);
        }
    }
    ushort4 o;
    o.x = f2bf(acc.x); o.y = f2bf(acc.y); o.z = f2bf(acc.z); o.w = f2bf(acc.w);
    agg[(size_t)node * 64 + lane] = o;
}

// ================= GEMM =================
// A: bf16 (ABF16) or f32 (optionally BN+ReLU fused in staging). C: f32 or bf16.
template<bool ABF16, bool BNSTAGE, bool OUTBF16>
__launch_bounds__(256)
__global__ void k_gemm(const void* __restrict__ Av, const unsigned short* __restrict__ Wf,
                       const float* __restrict__ bias,
                       const float* __restrict__ s1, const float* __restrict__ s2,
                       const float* __restrict__ g, const float* __restrict__ be,
                       void* __restrict__ Cv, int M) {
    __shared__ s16x8 Al[2048];   // 64 rows x 256 cols bf16 = 32 KB, XOR-swizzled
    const int tid = threadIdx.x;
    const int base_row = blockIdx.x * 64;

    #pragma unroll
    for (int i = 0; i < 8; i++) {
        int chunk = tid + i * 256;
        int row = chunk >> 5;
        int k0  = (chunk & 31) * 8;
        int gr = base_row + row;
        s16x8 sv;
        if constexpr (ABF16) {
            if (gr < M)
                sv = *(const s16x8*)((const unsigned short*)Av + (size_t)gr * 256 + k0);
            else
                sv = (s16x8){0,0,0,0,0,0,0,0};
        } else {
            float vv[8];
            if (gr < M) {
                const float4* gp = (const float4*)((const float*)Av + (size_t)gr * 256 + k0);
                float4 v0 = gp[0], v1 = gp[1];
                vv[0]=v0.x; vv[1]=v0.y; vv[2]=v0.z; vv[3]=v0.w;
                vv[4]=v1.x; vv[5]=v1.y; vv[6]=v1.z; vv[7]=v1.w;
            } else {
                #pragma unroll
                for (int j = 0; j < 8; j++) vv[j] = 0.f;
            }
            if constexpr (BNSTAGE) {
                #pragma unroll
                for (int j = 0; j < 8; j++) {
                    float m  = s1[k0+j] * (1.f/NN);
                    float var = s2[k0+j] * (1.f/NN) - m*m;
                    float kk = rsqrtf(var + 1e-5f) * g[k0+j];
                    float shv = be[k0+j] - m * kk;
                    vv[j] = fmaxf(vv[j] * kk + shv, 0.f);
                }
            }
            #pragma unroll
            for (int j = 0; j < 8; j++) sv[j] = (short)f2bf(vv[j]);
        }
        int byte = (row * 512 + k0 * 2) ^ ((row & 7) << 4);
        Al[byte >> 4] = sv;
    }
    __syncthreads();

    const int lane = tid & 63;
    const int w = tid >> 6;
    const int wr = w >> 1;
    const int wc = w & 1;

    f32x4 acc[2][8];
    #pragma unroll
    for (int m = 0; m < 2; m++)
        #pragma unroll
        for (int c = 0; c < 8; c++)
            acc[m][c] = (f32x4){0.f, 0.f, 0.f, 0.f};

    #pragma unroll
    for (int s = 0; s < 8; s++) {
        s16x8 a[2], b[8];
        #pragma unroll
        for (int m = 0; m < 2; m++) {
            int row = wr * 32 + m * 16 + (lane & 15);
            int koff = s * 32 + (lane >> 4) * 8;
            int byte = (row * 512 + koff * 2) ^ ((row & 7) << 4);
            a[m] = Al[byte >> 4];
        }
        const unsigned short* wp = Wf + (size_t)((s * 16 + wc * 8) * 64 + lane) * 8;
        #pragma unroll
        for (int c = 0; c < 8; c++)
            b[c] = *(const s16x8*)(wp + (size_t)c * 512);
        #pragma unroll
        for (int m = 0; m < 2; m++)
            #pragma unroll
            for (int c = 0; c < 8; c++)
                acc[m][c] = __builtin_amdgcn_mfma_f32_16x16x32_bf16(a[m], b[c], acc[m][c], 0, 0, 0);
    }

    #pragma unroll
    for (int m = 0; m < 2; m++) {
        int row0 = base_row + wr * 32 + m * 16 + (lane >> 4) * 4;
        #pragma unroll
        for (int c = 0; c < 8; c++) {
            int col = wc * 128 + c * 16 + (lane & 15);
            float bv = bias[col];
            #pragma unroll
            for (int r = 0; r < 4; r++) {
                int row = row0 + r;
                if (row < M) {
                    float v = acc[m][c][r] + bv;
                    if constexpr (OUTBF16)
                        ((unsigned short*)Cv)[(size_t)row * 256 + col] = f2bf(v);
                    else
                        ((float*)Cv)[(size_t)row * 256 + col] = v;
                }
            }
        }
    }
}

// ================= BN stats =================
__global__ void k_stats(const float* __restrict__ z, float* __restrict__ s1,
                        float* __restrict__ s2, int M) {
    int col = threadIdx.x;
    float a = 0.f, b = 0.f;
    for (int r = blockIdx.x; r < M; r += gridDim.x) {
        float v = z[(size_t)r * DD + col];
        a += v;
        b += v * v;
    }
    atomicAdd(&s1[col], a);
    atomicAdd(&s2[col], b);
}

__global__ void k_stats_bf(const unsigned short* __restrict__ z, float* __restrict__ s1,
                           float* __restrict__ s2, int M) {
    int col = threadIdx.x;
    float a = 0.f, b = 0.f;
    for (int r = blockIdx.x; r < M; r += gridDim.x) {
        float v = bf2f(z[(size_t)r * DD + col]);
        a += v;
        b += v * v;
    }
    atomicAdd(&s1[col], a);
    atomicAdd(&s2[col], b);
}

extern "C" void kernel_launch(void* const* d_in, const int* in_sizes, int n_in,
                              void* d_out, int out_size, void* d_ws, size_t ws_size,
                              hipStream_t stream) {
    const float* x   = (const float*)d_in[0];
    const int*   src = (const int*)d_in[1];
    const int*   dst = (const int*)d_in[2];
    const float* W[6]    = { (const float*)d_in[3],  (const float*)d_in[7],
                             (const float*)d_in[11], (const float*)d_in[15],
                             (const float*)d_in[19], (const float*)d_in[23] };
    const float* Bias[6] = { (const float*)d_in[4],  (const float*)d_in[8],
                             (const float*)d_in[12], (const float*)d_in[16],
                             (const float*)d_in[20], (const float*)d_in[24] };
    const float* Gam[5]  = { (const float*)d_in[5],  (const float*)d_in[9],
                             (const float*)d_in[13], (const float*)d_in[17],
                             (const float*)d_in[21] };
    const float* Bet[5]  = { (const float*)d_in[6],  (const float*)d_in[10],
                             (const float*)d_in[14], (const float*)d_in[18],
                             (const float*)d_in[22] };

    char* ws = (char*)d_ws;
    unsigned short* Wf = (unsigned short*)ws;              // 786,432 B
    float* stats = (float*)(ws + 786432);                  // 10,240 B
    unsigned short* aggbf = (unsigned short*)(ws + (1 << 20));       // 51.2 MB
    unsigned short* z2bf  = aggbf + (size_t)NN * DD;                 // 51.2 MB
    char* csr = ws + (1 << 20) + 102400000;
    int* rowptr = (int*)csr;
    int* deg    = (int*)(csr + 400128);
    int* cur    = (int*)(csr + 800128);
    int* bsum   = (int*)(csr + 1200128);
    int* boff   = (int*)(csr + 1202176);
    int* eidx   = (int*)(csr + 1204224);
    float* OUT = (float*)d_out;

    // ---- prep
    for (int i = 0; i < 6; i++)
        k_wconv<<<256, 256, 0, stream>>>(W[i], Wf + (size_t)i * 65536);
    hipMemsetAsync(stats, 0, 5 * 512 * sizeof(float), stream);
    hipMemsetAsync(deg, 0, NN * sizeof(int), stream);
    hipMemsetAsync(cur, 0, NN * sizeof(int), stream);

    k_deghist<<<EE / 256, 256, 0, stream>>>(dst, deg);
    k_blocksum<<<NB, 256, 0, stream>>>(deg, bsum);
    k_scanb<<<1, 512, 0, stream>>>(bsum, boff, rowptr);
    k_finalscan<<<NB, 256, 0, stream>>>(deg, boff, rowptr);
    k_fill<<<EE / 256, 256, 0, stream>>>(src, dst, rowptr, cur, eidx);

    const int GG = (NN * 64 + 255) / 256;
    float* st[5];
    for (int i = 0; i < 5; i++) st[i] = stats + i * 512;

    auto gemm1 = [&](const unsigned short* A, int wi, float* C) {   // bf16 A -> f32 C
        k_gemm<true, false, false><<<1563, 256, 0, stream>>>(
            A, Wf + (size_t)wi * 65536, Bias[wi], nullptr, nullptr, nullptr, nullptr, C, NN);
    };
    auto gemm2bf = [&](const float* A, int wi, int si, unsigned short* C) { // f32+BN A -> bf16 C
        k_gemm<false, true, true><<<1563, 256, 0, stream>>>(
            A, Wf + (size_t)wi * 65536, Bias[wi], st[si], st[si] + 256, Gam[si], Bet[si], C, NN);
    };

    // ---- Layer 0
    k_gather<0><<<GG, 256, 0, stream>>>(x, rowptr, eidx, nullptr, nullptr, nullptr, nullptr,
                                        (ushort4*)aggbf);
    gemm1(aggbf, 0, OUT);
    k_stats<<<1024, 256, 0, stream>>>(OUT, st[0], st[0] + 256, NN);
    gemm2bf(OUT, 1, 0, z2bf);
    k_stats_bf<<<1024, 256, 0, stream>>>(z2bf, st[1], st[1] + 256, NN);

    // ---- Layer 1
    k_gather<1><<<GG, 256, 0, stream>>>(z2bf, rowptr, eidx, st[1], st[1] + 256, Gam[1], Bet[1],
                                        (ushort4*)aggbf);
    gemm1(aggbf, 2, OUT);
    k_stats<<<1024, 256, 0, stream>>>(OUT, st[2], st[2] + 256, NN);
    gemm2bf(OUT, 3, 2, z2bf);
    k_stats_bf<<<1024, 256, 0, stream>>>(z2bf, st[3], st[3] + 256, NN);

    // ---- Layer 2
    k_gather<1><<<GG, 256, 0, stream>>>(z2bf, rowptr, eidx, st[3], st[3] + 256, Gam[3], Bet[3],
                                        (ushort4*)aggbf);
    gemm1(aggbf, 4, OUT);
    k_stats<<<1024, 256, 0, stream>>>(OUT, st[4], st[4] + 256, NN);
    // final: f32 z1 in OUT -> BN+ReLU staged -> GEMM -> f32 OUT (in-place safe)
    k_gemm<false, true, false><<<1563, 256, 0, stream>>>(
        OUT, Wf + (size_t)5 * 65536, Bias[5], st[4], st[4] + 256, Gam[4], Bet[4], OUT, NN);
}

// Round 4
// 1150.156 us; speedup vs baseline: 14.5542x; 1.0819x over previous
//
#include <hip/hip_runtime.h>
#include <hip/hip_bf16.h>
#include <stdint.h>

#define NN 100000
#define DD 256
#define EE 1600000
#define NB 391   // ceil(NN/256)

typedef short s16x8 __attribute__((ext_vector_type(8)));
typedef float f32x4 __attribute__((ext_vector_type(4)));

__device__ __forceinline__ unsigned short f2bf(float f) {
    union { float f; unsigned int u; } un; un.f = f;
    unsigned int u = un.u;
    unsigned int r = u + 0x7fffu + ((u >> 16) & 1u);  // RNE
    return (unsigned short)(r >> 16);
}
__device__ __forceinline__ float bf2f(unsigned short s) {
    union { unsigned int u; float f; } c; c.u = (unsigned int)s << 16; return c.f;
}

// ---- weight -> MFMA B-fragment order
__global__ void k_wconv(const float* __restrict__ W, unsigned short* __restrict__ Wf) {
    int t = blockIdx.x * 256 + threadIdx.x;   // 65536 total
    int j = t & 7;
    int l = (t >> 3) & 63;
    int c = (t >> 9) & 15;
    int s = t >> 13;
    int k   = s * 32 + (l >> 4) * 8 + j;
    int col = c * 16 + (l & 15);
    Wf[t] = f2bf(W[k * 256 + col]);
}

// ================= CSR build =================
__global__ void k_deghist(const int* __restrict__ dst, int* __restrict__ deg) {
    int e = blockIdx.x * 256 + threadIdx.x;
    atomicAdd(&deg[dst[e]], 1);
}

__global__ void k_blocksum(const int* __restrict__ deg, int* __restrict__ bsum) {
    __shared__ int s[256];
    int t = blockIdx.x * 256 + threadIdx.x;
    s[threadIdx.x] = (t < NN) ? deg[t] : 0;
    __syncthreads();
    for (int off = 128; off > 0; off >>= 1) {
        if (threadIdx.x < off) s[threadIdx.x] += s[threadIdx.x + off];
        __syncthreads();
    }
    if (threadIdx.x == 0) bsum[blockIdx.x] = s[0];
}

__global__ void k_scanb(const int* __restrict__ bsum, int* __restrict__ boff,
                        int* __restrict__ rowptr) {
    __shared__ int s[512];
    int tid = threadIdx.x;
    s[tid] = (tid < NB) ? bsum[tid] : 0;
    __syncthreads();
    for (int off = 1; off < 512; off <<= 1) {
        int x = 0;
        if (tid >= off) x = s[tid - off];
        __syncthreads();
        if (tid >= off) s[tid] += x;
        __syncthreads();
    }
    if (tid < NB) boff[tid] = (tid > 0) ? s[tid - 1] : 0;
    if (tid == 0) rowptr[NN] = EE;
}

__global__ void k_finalscan(const int* __restrict__ deg, const int* __restrict__ boff,
                            int* __restrict__ rowptr) {
    __shared__ int s[256];
    int tid = threadIdx.x;
    int t = blockIdx.x * 256 + tid;
    int v = (t < NN) ? deg[t] : 0;
    s[tid] = v;
    __syncthreads();
    for (int off = 1; off < 256; off <<= 1) {
        int x = 0;
        if (tid >= off) x = s[tid - off];
        __syncthreads();
        if (tid >= off) s[tid] += x;
        __syncthreads();
    }
    if (t < NN) rowptr[t] = boff[blockIdx.x] + s[tid] - v;  // exclusive
}

__global__ void k_fill(const int* __restrict__ src, const int* __restrict__ dst,
                       const int* __restrict__ rowptr, int* __restrict__ cur,
                       int* __restrict__ eidx) {
    int e = blockIdx.x * 256 + threadIdx.x;
    int d = dst[e];
    int pos = atomicAdd(&cur[d], 1);
    eidx[rowptr[d] + pos] = src[e];
}

// ================= gather =================
// MODE 0: f32 input, no BN (layer 0).  MODE 1: bf16 raw-z input, fused BN+ReLU.
// agg output bf16. One wave per node. 8-deep MLP pipeline.
template<int MODE>
__launch_bounds__(256)
__global__ void k_gather(const void* __restrict__ hv, const int* __restrict__ rowptr,
                         const int* __restrict__ eidx,
                         const float* __restrict__ s1, const float* __restrict__ s2,
                         const float* __restrict__ g, const float* __restrict__ be,
                         ushort4* __restrict__ agg) {
    int gid = blockIdx.x * 256 + threadIdx.x;
    int node = gid >> 6;
    int lane = gid & 63;
    if (node >= NN) return;
    int beg = rowptr[node];
    int end = rowptr[node + 1];
    float4 acc;

    if constexpr (MODE == 0) {
        const float4* h = (const float4*)hv;
        acc = h[(size_t)node * 64 + lane];
        int i = beg;
        for (; i + 8 <= end; i += 8) {
            int idx[8];
            #pragma unroll
            for (int j = 0; j < 8; j++) idx[j] = eidx[i + j];
            float4 v[8];
            #pragma unroll
            for (int j = 0; j < 8; j++) v[j] = h[(size_t)idx[j] * 64 + lane];
            #pragma unroll
            for (int j = 0; j < 8; j++) {
                acc.x += v[j].x; acc.y += v[j].y; acc.z += v[j].z; acc.w += v[j].w;
            }
        }
        for (; i + 4 <= end; i += 4) {
            int idx[4];
            #pragma unroll
            for (int j = 0; j < 4; j++) idx[j] = eidx[i + j];
            float4 v[4];
            #pragma unroll
            for (int j = 0; j < 4; j++) v[j] = h[(size_t)idx[j] * 64 + lane];
            #pragma unroll
            for (int j = 0; j < 4; j++) {
                acc.x += v[j].x; acc.y += v[j].y; acc.z += v[j].z; acc.w += v[j].w;
            }
        }
        for (; i + 2 <= end; i += 2) {
            float4 v0 = h[(size_t)eidx[i] * 64 + lane];
            float4 v1 = h[(size_t)eidx[i + 1] * 64 + lane];
            acc.x += v0.x + v1.x; acc.y += v0.y + v1.y;
            acc.z += v0.z + v1.z; acc.w += v0.w + v1.w;
        }
        if (i < end) {
            float4 v = h[(size_t)eidx[i] * 64 + lane];
            acc.x += v.x; acc.y += v.y; acc.z += v.z; acc.w += v.w;
        }
    } else {
        const ushort4* h = (const ushort4*)hv;
        int c0 = lane * 4;
        float4 s1v = *(const float4*)(s1 + c0);
        float4 s2v = *(const float4*)(s2 + c0);
        float4 gv  = *(const float4*)(g + c0);
        float4 bev = *(const float4*)(be + c0);
        float kk[4], sh[4];
        {
            float m, var;
            m = s1v.x * (1.f/NN); var = s2v.x * (1.f/NN) - m*m; kk[0] = rsqrtf(var+1e-5f)*gv.x; sh[0] = bev.x - m*kk[0];
            m = s1v.y * (1.f/NN); var = s2v.y * (1.f/NN) - m*m; kk[1] = rsqrtf(var+1e-5f)*gv.y; sh[1] = bev.y - m*kk[1];
            m = s1v.z * (1.f/NN); var = s2v.z * (1.f/NN) - m*m; kk[2] = rsqrtf(var+1e-5f)*gv.z; sh[2] = bev.z - m*kk[2];
            m = s1v.w * (1.f/NN); var = s2v.w * (1.f/NN) - m*m; kk[3] = rsqrtf(var+1e-5f)*gv.w; sh[3] = bev.w - m*kk[3];
        }
        ushort4 u = h[(size_t)node * 64 + lane];
        acc.x = fmaxf(bf2f(u.x) * kk[0] + sh[0], 0.f);
        acc.y = fmaxf(bf2f(u.y) * kk[1] + sh[1], 0.f);
        acc.z = fmaxf(bf2f(u.z) * kk[2] + sh[2], 0.f);
        acc.w = fmaxf(bf2f(u.w) * kk[3] + sh[3], 0.f);
        int i = beg;
        for (; i + 8 <= end; i += 8) {
            int idx[8];
            #pragma unroll
            for (int j = 0; j < 8; j++) idx[j] = eidx[i + j];
            ushort4 v[8];
            #pragma unroll
            for (int j = 0; j < 8; j++) v[j] = h[(size_t)idx[j] * 64 + lane];
            #pragma unroll
            for (int j = 0; j < 8; j++) {
                acc.x += fmaxf(bf2f(v[j].x) * kk[0] + sh[0], 0.f);
                acc.y += fmaxf(bf2f(v[j].y) * kk[1] + sh[1], 0.f);
                acc.z += fmaxf(bf2f(v[j].z) * kk[2] + sh[2], 0.f);
                acc.w += fmaxf(bf2f(v[j].w) * kk[3] + sh[3], 0.f);
            }
        }
        for (; i + 4 <= end; i += 4) {
            int idx[4];
            #pragma unroll
            for (int j = 0; j < 4; j++) idx[j] = eidx[i + j];
            ushort4 v[4];
            #pragma unroll
            for (int j = 0; j < 4; j++) v[j] = h[(size_t)idx[j] * 64 + lane];
            #pragma unroll
            for (int j = 0; j < 4; j++) {
                acc.x += fmaxf(bf2f(v[j].x) * kk[0] + sh[0], 0.f);
                acc.y += fmaxf(bf2f(v[j].y) * kk[1] + sh[1], 0.f);
                acc.z += fmaxf(bf2f(v[j].z) * kk[2] + sh[2], 0.f);
                acc.w += fmaxf(bf2f(v[j].w) * kk[3] + sh[3], 0.f);
            }
        }
        for (; i < end; i++) {
            ushort4 a = h[(size_t)eidx[i] * 64 + lane];
            acc.x += fmaxf(bf2f(a.x) * kk[0] + sh[0], 0.f);
            acc.y += fmaxf(bf2f(a.y) * kk[1] + sh[1], 0.f);
            acc.z += fmaxf(bf2f(a.z) * kk[2] + sh[2], 0.f);
            acc.w += fmaxf(bf2f(a.w) * kk[3] + sh[3], 0.f);
        }
    }
    ushort4 o;
    o.x = f2bf(acc.x); o.y = f2bf(acc.y); o.z = f2bf(acc.z); o.w = f2bf(acc.w);
    agg[(size_t)node * 64 + lane] = o;
}

// ================= GEMM =================
// A: bf16 (ABF16) or f32 (opt. fused BN+ReLU in staging). C: f32 or bf16.
// STATS: fused per-column sum / sum-sq of C into s1o/s2o (pre-zeroed, atomics).
template<bool ABF16, bool BNSTAGE, bool OUTBF16, bool STATS>
__launch_bounds__(256)
__global__ void k_gemm(const void* __restrict__ Av, const unsigned short* __restrict__ Wf,
                       const float* __restrict__ bias,
                       const float* __restrict__ s1, const float* __restrict__ s2,
                       const float* __restrict__ g, const float* __restrict__ be,
                       void* __restrict__ Cv,
                       float* __restrict__ s1o, float* __restrict__ s2o, int M) {
    __shared__ s16x8 Al[2048];   // 64 rows x 256 cols bf16 = 32 KB, XOR-swizzled
    __shared__ float sbn[512];
    const int tid = threadIdx.x;
    const int base_row = blockIdx.x * 64;

    if constexpr (STATS) {
        sbn[tid] = 0.f; sbn[tid + 256] = 0.f;
    }

    #pragma unroll
    for (int i = 0; i < 8; i++) {
        int chunk = tid + i * 256;
        int row = chunk >> 5;
        int k0  = (chunk & 31) * 8;
        int gr = base_row + row;
        s16x8 sv;
        if constexpr (ABF16) {
            if (gr < M)
                sv = *(const s16x8*)((const unsigned short*)Av + (size_t)gr * 256 + k0);
            else
                sv = (s16x8){0,0,0,0,0,0,0,0};
        } else {
            float vv[8];
            if (gr < M) {
                const float4* gp = (const float4*)((const float*)Av + (size_t)gr * 256 + k0);
                float4 v0 = gp[0], v1 = gp[1];
                vv[0]=v0.x; vv[1]=v0.y; vv[2]=v0.z; vv[3]=v0.w;
                vv[4]=v1.x; vv[5]=v1.y; vv[6]=v1.z; vv[7]=v1.w;
            } else {
                #pragma unroll
                for (int j = 0; j < 8; j++) vv[j] = 0.f;
            }
            if constexpr (BNSTAGE) {
                #pragma unroll
                for (int j = 0; j < 8; j++) {
                    float m  = s1[k0+j] * (1.f/NN);
                    float var = s2[k0+j] * (1.f/NN) - m*m;
                    float kk = rsqrtf(var + 1e-5f) * g[k0+j];
                    float shv = be[k0+j] - m * kk;
                    vv[j] = fmaxf(vv[j] * kk + shv, 0.f);
                }
            }
            #pragma unroll
            for (int j = 0; j < 8; j++) sv[j] = (short)f2bf(vv[j]);
        }
        int byte = (row * 512 + k0 * 2) ^ ((row & 7) << 4);
        Al[byte >> 4] = sv;
    }
    __syncthreads();

    const int lane = tid & 63;
    const int w = tid >> 6;
    const int wr = w >> 1;
    const int wc = w & 1;

    f32x4 acc[2][8];
    #pragma unroll
    for (int m = 0; m < 2; m++)
        #pragma unroll
        for (int c = 0; c < 8; c++)
            acc[m][c] = (f32x4){0.f, 0.f, 0.f, 0.f};

    #pragma unroll
    for (int s = 0; s < 8; s++) {
        s16x8 a[2], b[8];
        #pragma unroll
        for (int m = 0; m < 2; m++) {
            int row = wr * 32 + m * 16 + (lane & 15);
            int koff = s * 32 + (lane >> 4) * 8;
            int byte = (row * 512 + koff * 2) ^ ((row & 7) << 4);
            a[m] = Al[byte >> 4];
        }
        const unsigned short* wp = Wf + (size_t)((s * 16 + wc * 8) * 64 + lane) * 8;
        #pragma unroll
        for (int c = 0; c < 8; c++)
            b[c] = *(const s16x8*)(wp + (size_t)c * 512);
        #pragma unroll
        for (int m = 0; m < 2; m++)
            #pragma unroll
            for (int c = 0; c < 8; c++)
                acc[m][c] = __builtin_amdgcn_mfma_f32_16x16x32_bf16(a[m], b[c], acc[m][c], 0, 0, 0);
    }

    #pragma unroll
    for (int m = 0; m < 2; m++) {
        int row0 = base_row + wr * 32 + m * 16 + (lane >> 4) * 4;
        #pragma unroll
        for (int c = 0; c < 8; c++) {
            int col = wc * 128 + c * 16 + (lane & 15);
            float bv = bias[col];
            float p1 = 0.f, p2 = 0.f;
            #pragma unroll
            for (int r = 0; r < 4; r++) {
                int row = row0 + r;
                if (row < M) {
                    float v = acc[m][c][r] + bv;
                    if constexpr (OUTBF16)
                        ((unsigned short*)Cv)[(size_t)row * 256 + col] = f2bf(v);
                    else
                        ((float*)Cv)[(size_t)row * 256 + col] = v;
                    if constexpr (STATS) { p1 += v; p2 += v * v; }
                }
            }
            if constexpr (STATS) {
                p1 += __shfl_xor(p1, 16); p1 += __shfl_xor(p1, 32);
                p2 += __shfl_xor(p2, 16); p2 += __shfl_xor(p2, 32);
                if (lane < 16) {
                    atomicAdd(&sbn[col], p1);
                    atomicAdd(&sbn[col + 256], p2);
                }
            }
        }
    }
    if constexpr (STATS) {
        __syncthreads();
        atomicAdd(&s1o[tid & 255], sbn[tid]);
        atomicAdd(&s2o[tid & 255], sbn[tid + 256]);
    }
}

extern "C" void kernel_launch(void* const* d_in, const int* in_sizes, int n_in,
                              void* d_out, int out_size, void* d_ws, size_t ws_size,
                              hipStream_t stream) {
    const float* x   = (const float*)d_in[0];
    const int*   src = (const int*)d_in[1];
    const int*   dst = (const int*)d_in[2];
    const float* W[6]    = { (const float*)d_in[3],  (const float*)d_in[7],
                             (const float*)d_in[11], (const float*)d_in[15],
                             (const float*)d_in[19], (const float*)d_in[23] };
    const float* Bias[6] = { (const float*)d_in[4],  (const float*)d_in[8],
                             (const float*)d_in[12], (const float*)d_in[16],
                             (const float*)d_in[20], (const float*)d_in[24] };
    const float* Gam[5]  = { (const float*)d_in[5],  (const float*)d_in[9],
                             (const float*)d_in[13], (const float*)d_in[17],
                             (const float*)d_in[21] };
    const float* Bet[5]  = { (const float*)d_in[6],  (const float*)d_in[10],
                             (const float*)d_in[14], (const float*)d_in[18],
                             (const float*)d_in[22] };

    char* ws = (char*)d_ws;
    unsigned short* Wf = (unsigned short*)ws;              // 786,432 B
    float* stats = (float*)(ws + 786432);                  // 10,240 B
    unsigned short* aggbf = (unsigned short*)(ws + (1 << 20));       // 51.2 MB
    unsigned short* z2bf  = aggbf + (size_t)NN * DD;                 // 51.2 MB
    char* csr = ws + (1 << 20) + 102400000;
    int* rowptr = (int*)csr;
    int* deg    = (int*)(csr + 400128);
    int* cur    = (int*)(csr + 800128);
    int* bsum   = (int*)(csr + 1200128);
    int* boff   = (int*)(csr + 1202176);
    int* eidx   = (int*)(csr + 1204224);
    float* OUT = (float*)d_out;

    // ---- prep
    for (int i = 0; i < 6; i++)
        k_wconv<<<256, 256, 0, stream>>>(W[i], Wf + (size_t)i * 65536);
    hipMemsetAsync(stats, 0, 5 * 512 * sizeof(float), stream);
    hipMemsetAsync(deg, 0, NN * sizeof(int), stream);
    hipMemsetAsync(cur, 0, NN * sizeof(int), stream);

    k_deghist<<<EE / 256, 256, 0, stream>>>(dst, deg);
    k_blocksum<<<NB, 256, 0, stream>>>(deg, bsum);
    k_scanb<<<1, 512, 0, stream>>>(bsum, boff, rowptr);
    k_finalscan<<<NB, 256, 0, stream>>>(deg, boff, rowptr);
    k_fill<<<EE / 256, 256, 0, stream>>>(src, dst, rowptr, cur, eidx);

    const int GG = (NN * 64 + 255) / 256;
    float* st[5];
    for (int i = 0; i < 5; i++) st[i] = stats + i * 512;

    // bf16 A -> f32 C, fused stats
    auto gemm1 = [&](const unsigned short* A, int wi, int si, float* C) {
        k_gemm<true, false, false, true><<<1563, 256, 0, stream>>>(
            A, Wf + (size_t)wi * 65536, Bias[wi], nullptr, nullptr, nullptr, nullptr,
            C, st[si], st[si] + 256, NN);
    };
    // f32 A + BN staged -> bf16 C, fused stats
    auto gemm2bf = [&](const float* A, int wi, int si, int so, unsigned short* C) {
        k_gemm<false, true, true, true><<<1563, 256, 0, stream>>>(
            A, Wf + (size_t)wi * 65536, Bias[wi], st[si], st[si] + 256, Gam[si], Bet[si],
            C, st[so], st[so] + 256, NN);
    };

    // ---- Layer 0
    k_gather<0><<<GG, 256, 0, stream>>>(x, rowptr, eidx, nullptr, nullptr, nullptr, nullptr,
                                        (ushort4*)aggbf);
    gemm1(aggbf, 0, 0, OUT);
    gemm2bf(OUT, 1, 0, 1, z2bf);

    // ---- Layer 1
    k_gather<1><<<GG, 256, 0, stream>>>(z2bf, rowptr, eidx, st[1], st[1] + 256, Gam[1], Bet[1],
                                        (ushort4*)aggbf);
    gemm1(aggbf, 2, 2, OUT);
    gemm2bf(OUT, 3, 2, 3, z2bf);

    // ---- Layer 2
    k_gather<1><<<GG, 256, 0, stream>>>(z2bf, rowptr, eidx, st[3], st[3] + 256, Gam[3], Bet[3],
                                        (ushort4*)aggbf);
    gemm1(aggbf, 4, 4, OUT);
    // final: f32 z1 in OUT -> BN+ReLU staged -> GEMM -> f32 OUT (in-place safe), no stats
    k_gemm<false, true, false, false><<<1563, 256, 0, stream>>>(
        OUT, Wf + (size_t)5 * 65536, Bias[5], st[4], st[4] + 256, Gam[4], Bet[4],
        OUT, nullptr, nullptr, NN);
}